// Round 2
// baseline (2215.885 us; speedup 1.0000x reference)
//
#include <hip/hip_runtime.h>
#include <hip/hip_bf16.h>
#include <cstdint>
#include <cstddef>

typedef __bf16 bf16_t;
typedef bf16_t bf16x8 __attribute__((ext_vector_type(8)));
typedef bf16_t bf16x4 __attribute__((ext_vector_type(4)));
typedef float  f32x4  __attribute__((ext_vector_type(4)));

#define TT    64
#define T_CTX 24
#define HOR   40
#define ST    136     // LDS row stride (elems): 272B, 16B-aligned, 2-way bank (free)
#define NTH   512     // 8 waves

#define MFMA __builtin_amdgcn_mfma_f32_16x16x32_bf16

// ---- canonical bf16 weight layout in d_ws (element offsets; flag in elems 0..7) ----
#define O_WIH0   16
#define O_WHH0   (O_WIH0  + 65536)
#define O_WIH1   (O_WHH0  + 65536)
#define O_WHH1   (O_WIH1  + 65536)
#define O_INWIH  (O_WHH1  + 65536)
#define O_INWHH  (O_INWIH + 131072)
#define O_L1WIH  (O_INWHH + 65536)
#define O_L1WHH  (O_L1WIH + 65536)
#define O_HIW1   (O_L1WHH + 65536)
#define O_HOW1   (O_HIW1  + 16384)
#define O_BIAS   (O_HOW1  + 16384)   // 4 x 512 (enc0, enc1, in, l1), bih+bhh
#define O_HEADP  (O_BIAS  + 2048)    // h2inb1|h2inW2|h2outb1|h2outW2 (4 x 128)
#define O_WINE   (O_HEADP + 512)     // enc_W_in rows padded to 12
#define O_WINN   (O_WINE  + 1536)    // node_W_in rows padded to 12
#define O_B2     (O_WINN  + 1536)    // h2inb2, h2outb2

struct Ptrs { const void* q[29]; };

__device__ __forceinline__ float sigm(float x) {
  return __builtin_amdgcn_rcpf(1.f + __expf(-x));
}
__device__ __forceinline__ float tanh_(float x) {
  return 1.f - 2.f * __builtin_amdgcn_rcpf(1.f + __expf(2.f * x));
}
__device__ __forceinline__ unsigned pk2(float a, float b) {   // 2x fp32 -> packed bf16 (RNE)
  unsigned ua = __float_as_uint(a), ub = __float_as_uint(b);
  ua = (ua + 0x7fffu + ((ua >> 16) & 1u)) >> 16;
  ub = (ub + 0x7fffu + ((ub >> 16) & 1u)) >> 16;
  return ua | (ub << 16);
}
__device__ __forceinline__ float uplo(unsigned p){ return __uint_as_float(p << 16); }
__device__ __forceinline__ float uphi(unsigned p){ return __uint_as_float(p & 0xffff0000u); }

// ================= dtype detector =================
// Reads enc_Wih0 (weights ~N(0, 0.088)) as bf16. If the buffer is really fp32,
// ~40% of 16-bit halves decode to wild exponents; if bf16, ~none do.
__global__ void detect_kernel(const unsigned short* __restrict__ wsrc, int* __restrict__ flag)
{
  int tid = threadIdx.x;
  int wild = 0;
  for (int i = tid; i < 256; i += 64) {
    unsigned short b = wsrc[i];
    float v  = __uint_as_float(((unsigned)b) << 16);
    float av = fabsf(v);
    unsigned e = (b >> 7) & 0xff;
    if (av > 1000.f || e == 0xff || (((b & 0x7fff) != 0) && av < 1e-9f)) wild++;
  }
  for (int off = 32; off; off >>= 1) wild += __shfl_down(wild, off, 64);
  if (tid == 0) flag[0] = (wild > 16) ? 1 : 0;   // 1 = fp32 buffers, 0 = bf16
}

// ================= weight prep: convert everything to canonical bf16 in ws =================
__global__ void prep_kernel(Ptrs P, bf16_t* __restrict__ w, const int* __restrict__ flag)
{
  const bool f32 = (flag[0] != 0);
  const int gtid = blockIdx.x * blockDim.x + threadIdx.x;
  const int gsz  = gridDim.x * blockDim.x;

  auto rd = [&](const void* src, int i) -> float {
    return f32 ? ((const float*)src)[i] : (float)((const bf16_t*)src)[i];
  };
  auto cp = [&](const void* src, int dst, int n) {
    if (f32) { const float*  s = (const float*)src;
      for (int i = gtid; i < n; i += gsz) w[dst + i] = (bf16_t)s[i];
    } else   { const bf16_t* s = (const bf16_t*)src;
      for (int i = gtid; i < n; i += gsz) w[dst + i] = s[i];
    }
  };

  cp(P.q[4],  O_WIH0,  65536);   // enc_Wih0
  cp(P.q[5],  O_WHH0,  65536);   // enc_Whh0
  cp(P.q[8],  O_WIH1,  65536);   // enc_Wih1
  cp(P.q[9],  O_WHH1,  65536);   // enc_Whh1
  cp(P.q[13], O_INWIH, 131072);  // in_Wih
  cp(P.q[14], O_INWHH, 65536);   // in_Whh
  cp(P.q[17], O_L1WIH, 65536);   // l1_Wih
  cp(P.q[18], O_L1WHH, 65536);   // l1_Whh
  cp(P.q[21], O_HIW1,  16384);   // h2in_W1
  cp(P.q[25], O_HOW1,  16384);   // h2out_W1

  for (int i = gtid; i < 512; i += gsz) {
    w[O_BIAS + i]        = (bf16_t)(rd(P.q[6],  i) + rd(P.q[7],  i));   // enc0
    w[O_BIAS + 512 + i]  = (bf16_t)(rd(P.q[10], i) + rd(P.q[11], i));   // enc1
    w[O_BIAS + 1024 + i] = (bf16_t)(rd(P.q[15], i) + rd(P.q[16], i));   // in
    w[O_BIAS + 1536 + i] = (bf16_t)(rd(P.q[19], i) + rd(P.q[20], i));   // l1
  }
  for (int i = gtid; i < 128; i += gsz) {
    w[O_HEADP + i]       = (bf16_t)rd(P.q[22], i);   // h2in_b1
    w[O_HEADP + 128 + i] = (bf16_t)rd(P.q[23], i);   // h2in_W2
    w[O_HEADP + 256 + i] = (bf16_t)rd(P.q[26], i);   // h2out_b1
    w[O_HEADP + 384 + i] = (bf16_t)rd(P.q[27], i);   // h2out_W2
  }
  for (int i = gtid; i < 1536; i += gsz) {
    int cc = i / 12, j = i % 12;
    w[O_WINE + i] = (j < 10) ? (bf16_t)rd(P.q[3],  cc * 10 + j) : (bf16_t)0.f;
    w[O_WINN + i] = (j < 10) ? (bf16_t)rd(P.q[12], cc * 10 + j) : (bf16_t)0.f;
  }
  if (gtid == 0) {
    w[O_B2]     = (bf16_t)rd(P.q[24], 0);
    w[O_B2 + 1] = (bf16_t)rd(P.q[28], 0);
  }
}

// gates[64, 512] += A[64, 32*NKT] @ W[:, kofs:+32*NKT]^T   (W row-major [512][rs])
template<int NKT>
__device__ __forceinline__ void gemm_bt(f32x4 (&acc)[4][4], const bf16_t* __restrict__ As,
                                        const bf16_t* __restrict__ W, int rs, int kofs,
                                        int wid, int l, int q)
{
#pragma unroll
  for (int kt = 0; kt < NKT; ++kt) {
    const int k0 = kt * 32 + q * 8;
    bf16x8 a0 = *(const bf16x8*)(As + (0 * 16 + l) * ST + k0);
    bf16x8 a1 = *(const bf16x8*)(As + (1 * 16 + l) * ST + k0);
    bf16x8 a2 = *(const bf16x8*)(As + (2 * 16 + l) * ST + k0);
    bf16x8 a3 = *(const bf16x8*)(As + (3 * 16 + l) * ST + k0);
#pragma unroll
    for (int g = 0; g < 4; ++g) {
      bf16x8 b = *(const bf16x8*)(W + (size_t)(g * 128 + wid * 16 + l) * rs + kofs + k0);
      acc[g][0] = MFMA(a0, b, acc[g][0], 0, 0, 0);
      acc[g][1] = MFMA(a1, b, acc[g][1], 0, 0, 0);
      acc[g][2] = MFMA(a2, b, acc[g][2], 0, 0, 0);
      acc[g][3] = MFMA(a3, b, acc[g][3], 0, 0, 0);
    }
  }
}

__device__ __forceinline__ void cell_update(f32x4 (&acc)[4][4], float (&c)[16],
                                            bf16_t* __restrict__ sh,
                                            const bf16_t* __restrict__ bias,
                                            int wid, int l, int q)
{
  const int jc = wid * 16 + l;
  const float bi  = (float)bias[jc];
  const float bf_ = (float)bias[128 + jc];
  const float bg  = (float)bias[256 + jc];
  const float bo  = (float)bias[384 + jc];
#pragma unroll
  for (int mt = 0; mt < 4; ++mt) {
#pragma unroll
    for (int r = 0; r < 4; ++r) {
      float gi = acc[0][mt][r] + bi;
      float gf = acc[1][mt][r] + bf_;
      float gg = acc[2][mt][r] + bg;
      float go = acc[3][mt][r] + bo;
      float cn = sigm(gf) * c[mt * 4 + r] + sigm(gi) * tanh_(gg);
      float hh = sigm(go) * tanh_(cn);
      c[mt * 4 + r] = cn;
      sh[(mt * 16 + q * 4 + r) * ST + jc] = (bf16_t)hh;
    }
  }
}

__device__ __forceinline__ void proj16(const float* v, const bf16_t* __restrict__ wbase,
                                       bf16_t* __restrict__ sx, int nd, int sub)
{
  bf16x8 o0, o1;
#pragma unroll
  for (int cc = 0; cc < 16; ++cc) {
    const bf16_t* wr = wbase + (sub * 16 + cc) * 12;
    bf16x4 w0 = *(const bf16x4*)(wr);
    bf16x4 w1 = *(const bf16x4*)(wr + 4);
    bf16x4 w2 = *(const bf16x4*)(wr + 8);
    float a = v[0] * (float)w0[0] + v[1] * (float)w0[1] + v[2] * (float)w0[2] + v[3] * (float)w0[3]
            + v[4] * (float)w1[0] + v[5] * (float)w1[1] + v[6] * (float)w1[2] + v[7] * (float)w1[3]
            + v[8] * (float)w2[0] + v[9] * (float)w2[1];
    if (cc < 8) o0[cc] = (bf16_t)a; else o1[cc - 8] = (bf16_t)a;
  }
  *(bf16x8*)(sx + nd * ST + sub * 16)     = o0;
  *(bf16x8*)(sx + nd * ST + sub * 16 + 8) = o1;
}

// ================= persistent LSTM kernel, templated on I/O dtype =================
template<typename T>
__global__ __launch_bounds__(NTH, 2) void lstm_persist(
    const T* __restrict__ x, const T* __restrict__ coords, const T* __restrict__ env,
    const bf16_t* __restrict__ w, const int* __restrict__ flag, T* __restrict__ out)
{
  const bool want_f32 = (sizeof(T) == 4);
  if ((flag[0] != 0) != want_f32) return;   // uniform exit: other variant handles it

  __shared__ __align__(16) bf16_t s_x [64 * ST];
  __shared__ __align__(16) bf16_t s_h0[64 * ST];
  __shared__ __align__(16) bf16_t s_h1[64 * ST];
  __shared__ __align__(16) bf16_t s_win[2 * 128 * 12];
  __shared__ __align__(16) bf16_t s_bias[4 * 512];
  __shared__ float s_red[128];
  __shared__ float s_xc[64];

  const int tid = threadIdx.x;
  const int wid = tid >> 6;
  const int l   = tid & 15;
  const int q   = (tid & 63) >> 4;
  const int node0 = blockIdx.x * 64;
  const int nd  = tid >> 3;
  const int sub = tid & 7;

  // ---------- preload from canonical ws ----------
  for (int i = tid; i < 2048; i += NTH) s_bias[i] = w[O_BIAS + i];
  for (int i = tid; i < 3072; i += NTH) s_win[i]  = w[O_WINE + i];
  for (int i = tid; i < 64 * ST; i += NTH) { s_h0[i] = (bf16_t)0.f; s_h1[i] = (bf16_t)0.f; }

  const float cx = (float)coords[(size_t)(node0 + nd) * 2 + 0];
  const float cy = (float)coords[(size_t)(node0 + nd) * 2 + 1];

  float c0[16], c1[16];
#pragma unroll
  for (int i = 0; i < 16; ++i) { c0[i] = 0.f; c1[i] = 0.f; }

  __syncthreads();

  // ================= encoder: 24 steps =================
#pragma unroll 1
  for (int t = 0; t < T_CTX; ++t) {
    float v[10];
    v[0] = (float)x[(size_t)(node0 + nd) * TT + t];
    v[1] = cx; v[2] = cy;
#pragma unroll
    for (int e = 0; e < 7; ++e)
      v[3 + e] = (float)env[((size_t)(node0 + nd) * 7 + e) * TT + t];
    proj16(v, s_win, s_x, nd, sub);
    __syncthreads();                                        // s_x ready

    f32x4 acc[4][4];
#pragma unroll
    for (int g = 0; g < 4; ++g)
#pragma unroll
      for (int mt = 0; mt < 4; ++mt) acc[g][mt] = f32x4{0.f, 0.f, 0.f, 0.f};
    gemm_bt<4>(acc, s_x,  w + O_WIH0, 128, 0, wid, l, q);
    gemm_bt<4>(acc, s_h0, w + O_WHH0, 128, 0, wid, l, q);
    __syncthreads();
    cell_update(acc, c0, s_h0, s_bias, wid, l, q);
    __syncthreads();                                        // s_h0 ready

#pragma unroll
    for (int g = 0; g < 4; ++g)
#pragma unroll
      for (int mt = 0; mt < 4; ++mt) acc[g][mt] = f32x4{0.f, 0.f, 0.f, 0.f};
    gemm_bt<4>(acc, s_h0, w + O_WIH1, 128, 0, wid, l, q);
    gemm_bt<4>(acc, s_h1, w + O_WHH1, 128, 0, wid, l, q);
    __syncthreads();
    cell_update(acc, c1, s_h1, s_bias + 512, wid, l, q);
  }
  __syncthreads();                                          // encoder-final s_h1 visible

  // ---- enc_state @ in_Wih[:,128:256]^T once; keep hi+lo bf16 split (~2^-16 rel) ----
  uint2 geh[4][4], gel[4][4];
  {
    f32x4 acc[4][4];
#pragma unroll
    for (int g = 0; g < 4; ++g)
#pragma unroll
      for (int mt = 0; mt < 4; ++mt) acc[g][mt] = f32x4{0.f, 0.f, 0.f, 0.f};
    gemm_bt<4>(acc, s_h1, w + O_INWIH, 256, 128, wid, l, q);
#pragma unroll
    for (int g = 0; g < 4; ++g)
#pragma unroll
      for (int mt = 0; mt < 4; ++mt) {
        unsigned hx = pk2(acc[g][mt][0], acc[g][mt][1]);
        unsigned hy = pk2(acc[g][mt][2], acc[g][mt][3]);
        geh[g][mt] = uint2{hx, hy};
        gel[g][mt] = uint2{pk2(acc[g][mt][0] - uplo(hx), acc[g][mt][1] - uphi(hx)),
                           pk2(acc[g][mt][2] - uplo(hy), acc[g][mt][3] - uphi(hy))};
      }
  }
  if (tid < 64) s_xc[tid] = (float)x[(size_t)(node0 + tid) * TT + (T_CTX - 1)];
  const float b2i = (float)w[O_B2];
  const float b2o = (float)w[O_B2 + 1];
  const float b1i = (float)w[O_HEADP + wid * 16 + l];
  const float w2i = (float)w[O_HEADP + 128 + wid * 16 + l];
  const float b1o = (float)w[O_HEADP + 256 + wid * 16 + l];
  const float w2o = (float)w[O_HEADP + 384 + wid * 16 + l];
  __syncthreads();                                          // s_xc ready

  // ================= decoder: 40 steps =================
#pragma unroll 1
  for (int s = 0; s < HOR; ++s) {
    const int t = T_CTX + s;
    float v[10];
    v[0] = s_xc[nd];
    v[1] = cx; v[2] = cy;
#pragma unroll
    for (int e = 0; e < 7; ++e)
      v[3 + e] = (float)env[((size_t)(node0 + nd) * 7 + e) * TT + t];
    proj16(v, s_win + 1536, s_x, nd, sub);
    __syncthreads();                                        // s_x ready

    f32x4 acc[4][4];
#pragma unroll
    for (int g = 0; g < 4; ++g)
#pragma unroll
      for (int mt = 0; mt < 4; ++mt)
        acc[g][mt] = f32x4{uplo(geh[g][mt].x) + uplo(gel[g][mt].x),
                           uphi(geh[g][mt].x) + uphi(gel[g][mt].x),
                           uplo(geh[g][mt].y) + uplo(gel[g][mt].y),
                           uphi(geh[g][mt].y) + uphi(gel[g][mt].y)};
    gemm_bt<4>(acc, s_x,  w + O_INWIH, 256, 0, wid, l, q);
    gemm_bt<4>(acc, s_h0, w + O_INWHH, 128, 0, wid, l, q);
    __syncthreads();
    cell_update(acc, c0, s_h0, s_bias + 1024, wid, l, q);
    __syncthreads();                                        // s_h0 ready

#pragma unroll
    for (int g = 0; g < 4; ++g)
#pragma unroll
      for (int mt = 0; mt < 4; ++mt) acc[g][mt] = f32x4{0.f, 0.f, 0.f, 0.f};
    gemm_bt<4>(acc, s_h0, w + O_L1WIH, 128, 0, wid, l, q);
    gemm_bt<4>(acc, s_h1, w + O_L1WHH, 128, 0, wid, l, q);
    __syncthreads();
    cell_update(acc, c1, s_h1, s_bias + 1536, wid, l, q);
    if (tid < 128) s_red[tid] = 0.f;
    __syncthreads();                                        // s_h1 + s_red ready

    // ---- heads ----
    f32x4 hacc[2][4];
#pragma unroll
    for (int hd = 0; hd < 2; ++hd)
#pragma unroll
      for (int mt = 0; mt < 4; ++mt) hacc[hd][mt] = f32x4{0.f, 0.f, 0.f, 0.f};
#pragma unroll
    for (int kt = 0; kt < 4; ++kt) {
      const int k0 = kt * 32 + q * 8;
      bf16x8 a0 = *(const bf16x8*)(s_h1 + (0 * 16 + l) * ST + k0);
      bf16x8 a1 = *(const bf16x8*)(s_h1 + (1 * 16 + l) * ST + k0);
      bf16x8 a2 = *(const bf16x8*)(s_h1 + (2 * 16 + l) * ST + k0);
      bf16x8 a3 = *(const bf16x8*)(s_h1 + (3 * 16 + l) * ST + k0);
      bf16x8 bi_ = *(const bf16x8*)(w + O_HIW1 + (size_t)(wid * 16 + l) * 128 + k0);
      bf16x8 bo_ = *(const bf16x8*)(w + O_HOW1 + (size_t)(wid * 16 + l) * 128 + k0);
      hacc[0][0] = MFMA(a0, bi_, hacc[0][0], 0, 0, 0);
      hacc[0][1] = MFMA(a1, bi_, hacc[0][1], 0, 0, 0);
      hacc[0][2] = MFMA(a2, bi_, hacc[0][2], 0, 0, 0);
      hacc[0][3] = MFMA(a3, bi_, hacc[0][3], 0, 0, 0);
      hacc[1][0] = MFMA(a0, bo_, hacc[1][0], 0, 0, 0);
      hacc[1][1] = MFMA(a1, bo_, hacc[1][1], 0, 0, 0);
      hacc[1][2] = MFMA(a2, bo_, hacc[1][2], 0, 0, 0);
      hacc[1][3] = MFMA(a3, bo_, hacc[1][3], 0, 0, 0);
    }
#pragma unroll
    for (int hd = 0; hd < 2; ++hd) {
      const float b1v = hd ? b1o : b1i;
      const float w2v = hd ? w2o : w2i;
#pragma unroll
      for (int mt = 0; mt < 4; ++mt)
#pragma unroll
        for (int r = 0; r < 4; ++r) {
          float val = fmaxf(hacc[hd][mt][r] + b1v, 0.f) * w2v;
          val += __shfl_xor(val, 1, 64);
          val += __shfl_xor(val, 2, 64);
          val += __shfl_xor(val, 4, 64);
          val += __shfl_xor(val, 8, 64);
          if (l == 0) atomicAdd(&s_red[hd * 64 + mt * 16 + q * 4 + r], val);
        }
    }
    __syncthreads();                                        // s_red complete
    if (tid < 64) {
      float xc = s_xc[tid];
      float si = sigm(s_red[tid] + b2i);
      float so = sigm(s_red[64 + tid] + b2o);
      float xn = xc + si - so * xc;
      s_xc[tid] = xn;
      out[(size_t)(node0 + tid) * HOR + s] = (T)xn;
    }
    __syncthreads();                                        // s_xc stable for next proj
  }
}

extern "C" void kernel_launch(void* const* d_in, const int* in_sizes, int n_in,
                              void* d_out, int out_size, void* d_ws, size_t ws_size,
                              hipStream_t stream) {
  (void)in_sizes; (void)n_in; (void)out_size; (void)ws_size;
  Ptrs P;
  for (int i = 0; i < 29; ++i) P.q[i] = d_in[i];
  int*    flag = (int*)d_ws;
  bf16_t* w    = (bf16_t*)d_ws;   // element offsets start at 16 (flag lives in 0..7)

  detect_kernel<<<1, 64, 0, stream>>>((const unsigned short*)d_in[4], flag);
  prep_kernel<<<256, 256, 0, stream>>>(P, w, flag);
  lstm_persist<float><<<256, NTH, 0, stream>>>(
      (const float*)d_in[0], (const float*)d_in[1], (const float*)d_in[2],
      w, flag, (float*)d_out);
  lstm_persist<bf16_t><<<256, NTH, 0, stream>>>(
      (const bf16_t*)d_in[0], (const bf16_t*)d_in[1], (const bf16_t*)d_in[2],
      w, flag, (bf16_t*)d_out);
}

// Round 3
// 2159.492 us; speedup vs baseline: 1.0261x; 1.0261x over previous
//
#include <hip/hip_runtime.h>
#include <hip/hip_bf16.h>
#include <cstdint>
#include <cstddef>

typedef __bf16 bf16_t;
typedef bf16_t bf16x8 __attribute__((ext_vector_type(8)));
typedef bf16_t bf16x4 __attribute__((ext_vector_type(4)));
typedef float  f32x4  __attribute__((ext_vector_type(4)));

#define TT    64
#define T_CTX 24
#define HOR   40
#define SA    264     // LDS row stride (K=256 + 8 pad): 528B, 16B-aligned
#define NTH   512     // 8 waves

#define MFMA __builtin_amdgcn_mfma_f32_16x16x32_bf16

// ---- ws layout (bf16-element offsets; flag int at elem 0) ----
#define O_PKE   16                      // enc stream: 8 waves x 64 frags x 512
#define O_PKD   (O_PKE + 262144)        // dec stream: 8 x 72 x 512
#define O_PKX   (O_PKD + 294912)        // enc-term stream: 8 x 32 x 512
#define O_BIAS  (O_PKX + 131072)        // 4 x 512
#define O_HEADP (O_BIAS + 2048)         // h2in_b1|h2in_W2|h2out_b1|h2out_W2
#define O_WINE  (O_HEADP + 512)         // enc_W_in rows padded to 12
#define O_WINN  (O_WINE + 1536)
#define O_B2    (O_WINN + 1536)

struct Ptrs { const void* q[29]; };

__device__ __forceinline__ float sigm(float x) {
  return __builtin_amdgcn_rcpf(1.f + __expf(-x));
}
__device__ __forceinline__ float tanh_(float x) {
  return 1.f - 2.f * __builtin_amdgcn_rcpf(1.f + __expf(2.f * x));
}
__device__ __forceinline__ unsigned pk2(float a, float b) {
  unsigned ua = __float_as_uint(a), ub = __float_as_uint(b);
  ua = (ua + 0x7fffu + ((ua >> 16) & 1u)) >> 16;
  ub = (ub + 0x7fffu + ((ub >> 16) & 1u)) >> 16;
  return ua | (ub << 16);
}
__device__ __forceinline__ float uplo(unsigned p){ return __uint_as_float(p << 16); }
__device__ __forceinline__ float uphi(unsigned p){ return __uint_as_float(p & 0xffff0000u); }

// ================= dtype detector (unchanged, validated r2) =================
__global__ void detect_kernel(const unsigned short* __restrict__ wsrc, int* __restrict__ flag)
{
  int tid = threadIdx.x;
  int wild = 0;
  for (int i = tid; i < 256; i += 64) {
    unsigned short b = wsrc[i];
    float v  = __uint_as_float(((unsigned)b) << 16);
    float av = fabsf(v);
    unsigned e = (b >> 7) & 0xff;
    if (av > 1000.f || e == 0xff || (((b & 0x7fff) != 0) && av < 1e-9f)) wild++;
  }
  for (int off = 32; off; off >>= 1) wild += __shfl_down(wild, off, 64);
  if (tid == 0) flag[0] = (wild > 16) ? 1 : 0;
}

// ================= prep: pack weights into per-wave consumption-order streams =================
// Frag = 1KB: 64 lanes x 16B. Lane ln holds B-row (g*128 + w*16 + (ln&15)),
// k-cols kt*32 + (ln>>4)*8 .. +7  — exactly the 16x16x32 B-operand fragment.
__global__ void prep_kernel(Ptrs P, bf16_t* __restrict__ wb, const int* __restrict__ flag)
{
  const bool f32 = (flag[0] != 0);
  const int gtid = blockIdx.x * blockDim.x + threadIdx.x;
  const int gsz  = gridDim.x * blockDim.x;
  auto rd = [&](const void* src, int i) -> float {
    return f32 ? ((const float*)src)[i] : (float)((const bf16_t*)src)[i];
  };

  // E stream: [w][seg(E0|E1)][kt][g] frags
  for (int i = gtid; i < 262144; i += gsz) {
    int w = i >> 15, r = i & 32767, f = r >> 9, e = r & 511;
    int ln = e >> 3, j = e & 7;
    int seg = f >> 5, fk = f & 31, kt = fk >> 2, g = fk & 3;
    int row = g * 128 + w * 16 + (ln & 15);
    int col = kt * 32 + ((ln >> 4) << 3) + j;
    float v;
    if (seg == 0) v = (col < 128) ? rd(P.q[4], row * 128 + col) : rd(P.q[5], row * 128 + col - 128);
    else          v = (col < 128) ? rd(P.q[8], row * 128 + col) : rd(P.q[9], row * 128 + col - 128);
    wb[O_PKE + i] = (bf16_t)v;
  }
  // D stream: [w][D0(32)|D1(32)|H(8)]
  for (int i = gtid; i < 294912; i += gsz) {
    int w = i / 36864, r = i - w * 36864, f = r >> 9, e = r & 511;
    int ln = e >> 3, j = e & 7;
    int colk = ((ln >> 4) << 3) + j;
    float v;
    if (f < 64) {
      int seg = f >> 5, fk = f & 31, kt = fk >> 2, g = fk & 3;
      int row = g * 128 + w * 16 + (ln & 15);
      int col = kt * 32 + colk;
      if (seg == 0) v = (col < 128) ? rd(P.q[13], row * 256 + col) : rd(P.q[14], row * 128 + col - 128);
      else          v = (col < 128) ? rd(P.q[17], row * 128 + col) : rd(P.q[18], row * 128 + col - 128);
    } else {
      int f2 = f - 64, h = f2 >> 2, kt = f2 & 3;
      int row = w * 16 + (ln & 15);
      int col = kt * 32 + colk;
      v = rd(h ? P.q[25] : P.q[21], row * 128 + col);
    }
    wb[O_PKD + i] = (bf16_t)v;
  }
  // X stream: inWih[:, 128:256]
  for (int i = gtid; i < 131072; i += gsz) {
    int w = i >> 14, r = i & 16383, f = r >> 9, e = r & 511;
    int ln = e >> 3, j = e & 7;
    int kt = f >> 2, g = f & 3;
    int row = g * 128 + w * 16 + (ln & 15);
    int col = kt * 32 + ((ln >> 4) << 3) + j;
    wb[O_PKX + i] = (bf16_t)rd(P.q[13], row * 256 + 128 + col);
  }
  // biases / head params / input-proj weights
  for (int i = gtid; i < 512; i += gsz) {
    wb[O_BIAS + i]        = (bf16_t)(rd(P.q[6],  i) + rd(P.q[7],  i));
    wb[O_BIAS + 512 + i]  = (bf16_t)(rd(P.q[10], i) + rd(P.q[11], i));
    wb[O_BIAS + 1024 + i] = (bf16_t)(rd(P.q[15], i) + rd(P.q[16], i));
    wb[O_BIAS + 1536 + i] = (bf16_t)(rd(P.q[19], i) + rd(P.q[20], i));
  }
  for (int i = gtid; i < 128; i += gsz) {
    wb[O_HEADP + i]       = (bf16_t)rd(P.q[22], i);
    wb[O_HEADP + 128 + i] = (bf16_t)rd(P.q[23], i);
    wb[O_HEADP + 256 + i] = (bf16_t)rd(P.q[26], i);
    wb[O_HEADP + 384 + i] = (bf16_t)rd(P.q[27], i);
  }
  for (int i = gtid; i < 1536; i += gsz) {
    int cc = i / 12, j = i % 12;
    wb[O_WINE + i] = (j < 10) ? (bf16_t)rd(P.q[3],  cc * 10 + j) : (bf16_t)0.f;
    wb[O_WINN + i] = (j < 10) ? (bf16_t)rd(P.q[12], cc * 10 + j) : (bf16_t)0.f;
  }
  if (gtid == 0) {
    wb[O_B2]     = (bf16_t)rd(P.q[24], 0);
    wb[O_B2 + 1] = (bf16_t)rd(P.q[28], 0);
  }
}

// ================= main-kernel building blocks =================
struct PreB { bf16x8 b[2][4]; };   // first 2 kt (8 frags) of a stream

__device__ __forceinline__ PreB preB(const bf16_t* __restrict__ pl) {
  PreB r;
#pragma unroll
  for (int p = 0; p < 2; ++p)
#pragma unroll
    for (int g = 0; g < 4; ++g)
      r.b[p][g] = *(const bf16x8*)(pl + (p * 4 + g) * 512);
  return r;
}

// acc[g][mt] += A[64, 32*NKT](LDS, stride SA) @ Wstream^T ; rolling 3-kt window
template<int NKT>
__device__ __forceinline__ void gemm_pk(f32x4 (&acc)[4][4], const bf16_t* __restrict__ As,
                                        const bf16_t* __restrict__ pl, const PreB& pre,
                                        int l, int q)
{
  bf16x8 bw[3][4];
#pragma unroll
  for (int g = 0; g < 4; ++g) { bw[0][g] = pre.b[0][g]; bw[1][g] = pre.b[1][g]; }
#pragma unroll
  for (int kt = 0; kt < NKT; ++kt) {
    bf16x8 a[4];
#pragma unroll
    for (int mt = 0; mt < 4; ++mt)
      a[mt] = *(const bf16x8*)(As + (mt * 16 + l) * SA + kt * 32 + q * 8);
    if (kt + 2 < NKT) {
#pragma unroll
      for (int g = 0; g < 4; ++g)
        bw[(kt + 2) % 3][g] = *(const bf16x8*)(pl + ((kt + 2) * 4 + g) * 512);
    }
#pragma unroll
    for (int g = 0; g < 4; ++g) {
      bf16x8 b = bw[kt % 3][g];
      acc[g][0] = MFMA(a[0], b, acc[g][0], 0, 0, 0);
      acc[g][1] = MFMA(a[1], b, acc[g][1], 0, 0, 0);
      acc[g][2] = MFMA(a[2], b, acc[g][2], 0, 0, 0);
      acc[g][3] = MFMA(a[3], b, acc[g][3], 0, 0, 0);
    }
  }
}

// i,f,g,o for unit jc all in-lane (C layout: node=q*4+r within mt, unit=l). c in VGPRs.
template<bool DUAL>
__device__ __forceinline__ void cell_up(f32x4 (&acc)[4][4], float (&c)[16],
                                        bf16_t* __restrict__ shb, bf16_t* __restrict__ sha,
                                        const bf16_t* __restrict__ bias,
                                        int wid, int l, int q)
{
  const int jc = wid * 16 + l;
  const float bi  = (float)bias[jc];
  const float bf_ = (float)bias[128 + jc];
  const float bg  = (float)bias[256 + jc];
  const float bo  = (float)bias[384 + jc];
#pragma unroll
  for (int mt = 0; mt < 4; ++mt) {
#pragma unroll
    for (int r = 0; r < 4; ++r) {
      float gi = acc[0][mt][r] + bi;
      float gf = acc[1][mt][r] + bf_;
      float gg = acc[2][mt][r] + bg;
      float go = acc[3][mt][r] + bo;
      float cn = sigm(gf) * c[mt * 4 + r] + sigm(gi) * tanh_(gg);
      float hh = sigm(go) * tanh_(cn);
      c[mt * 4 + r] = cn;
      const int row = mt * 16 + q * 4 + r;
      shb[row * SA + jc] = (bf16_t)hh;
      if (DUAL) sha[row * SA + jc] = (bf16_t)hh;
    }
  }
}

__device__ __forceinline__ void proj16(const float* v, const bf16_t* __restrict__ wbase,
                                       bf16_t* __restrict__ sx, int nd, int sub)
{
  bf16x8 o0, o1;
#pragma unroll
  for (int cc = 0; cc < 16; ++cc) {
    const bf16_t* wr = wbase + (sub * 16 + cc) * 12;
    bf16x4 w0 = *(const bf16x4*)(wr);
    bf16x4 w1 = *(const bf16x4*)(wr + 4);
    bf16x4 w2 = *(const bf16x4*)(wr + 8);
    float a = v[0] * (float)w0[0] + v[1] * (float)w0[1] + v[2] * (float)w0[2] + v[3] * (float)w0[3]
            + v[4] * (float)w1[0] + v[5] * (float)w1[1] + v[6] * (float)w1[2] + v[7] * (float)w1[3]
            + v[8] * (float)w2[0] + v[9] * (float)w2[1];
    if (cc < 8) o0[cc] = (bf16_t)a; else o1[cc - 8] = (bf16_t)a;
  }
  *(bf16x8*)(sx + nd * SA + sub * 16)     = o0;
  *(bf16x8*)(sx + nd * SA + sub * 16 + 8) = o1;
}

// ================= persistent LSTM kernel =================
template<typename T>
__global__ __launch_bounds__(NTH, 2) void lstm_persist(
    const T* __restrict__ x, const T* __restrict__ coords, const T* __restrict__ env,
    const bf16_t* __restrict__ w, const int* __restrict__ flag, T* __restrict__ out)
{
  const bool want_f32 = (sizeof(T) == 4);
  if ((flag[0] != 0) != want_f32) return;

  __shared__ __align__(16) bf16_t bufA[64 * SA];   // [inp | h0]
  __shared__ __align__(16) bf16_t bufB[64 * SA];   // [h0 | h1]
  __shared__ __align__(16) bf16_t s_win[2 * 128 * 12];
  __shared__ __align__(16) bf16_t s_bias[4 * 512];
  __shared__ float s_red[128];
  __shared__ float s_xc[64];

  const int tid  = threadIdx.x;
  const int wid  = tid >> 6;
  const int lane = tid & 63;
  const int l    = tid & 15;
  const int q    = (tid & 63) >> 4;
  const int node0 = blockIdx.x * 64;
  const int nd  = tid >> 3;
  const int sub = tid & 7;

  const bf16_t* plE0 = w + O_PKE + wid * 32768 + lane * 8;
  const bf16_t* plE1 = plE0 + 16384;
  const bf16_t* plD0 = w + O_PKD + wid * 36864 + lane * 8;
  const bf16_t* plD1 = plD0 + 16384;
  const bf16_t* plH  = plD0 + 32768;
  const bf16_t* plX  = w + O_PKX + wid * 16384 + lane * 8;

  for (int i = tid; i < 2048; i += NTH) s_bias[i] = w[O_BIAS + i];
  for (int i = tid; i < 3072; i += NTH) s_win[i]  = w[O_WINE + i];
  for (int i = tid; i < 64 * SA; i += NTH) { bufA[i] = (bf16_t)0.f; bufB[i] = (bf16_t)0.f; }

  const float cx = (float)coords[(size_t)(node0 + nd) * 2 + 0];
  const float cy = (float)coords[(size_t)(node0 + nd) * 2 + 1];

  float c0[16], c1[16];
#pragma unroll
  for (int i = 0; i < 16; ++i) { c0[i] = 0.f; c1[i] = 0.f; }

  PreB pA = preB(plE0);
  __syncthreads();

  // ================= encoder =================
#pragma unroll 1
  for (int t = 0; t < T_CTX; ++t) {
    float v[10];
    v[0] = (float)x[(size_t)(node0 + nd) * TT + t];
    v[1] = cx; v[2] = cy;
#pragma unroll
    for (int e = 0; e < 7; ++e)
      v[3 + e] = (float)env[((size_t)(node0 + nd) * 7 + e) * TT + t];
    proj16(v, s_win, bufA, nd, sub);
    __syncthreads();                           // E1: bufA ready

    f32x4 acc[4][4];
#pragma unroll
    for (int g = 0; g < 4; ++g)
#pragma unroll
      for (int mt = 0; mt < 4; ++mt) acc[g][mt] = f32x4{0.f, 0.f, 0.f, 0.f};
    gemm_pk<8>(acc, bufA, plE0, pA, l, q);
    PreB pC = preB(plE1);
    __syncthreads();                           // E2: bufA consumed
    cell_up<true>(acc, c0, bufB, bufA + 128, s_bias, wid, l, q);
    __syncthreads();                           // E3: bufB[0:128] ready

#pragma unroll
    for (int g = 0; g < 4; ++g)
#pragma unroll
      for (int mt = 0; mt < 4; ++mt) acc[g][mt] = f32x4{0.f, 0.f, 0.f, 0.f};
    gemm_pk<8>(acc, bufB, plE1, pC, l, q);
    pA = preB((t < T_CTX - 1) ? plE0 : plX);
    __syncthreads();                           // E4: bufB consumed
    cell_up<false>(acc, c1, bufB + 128, nullptr, s_bias + 512, wid, l, q);
  }
  __syncthreads();                             // enc-final h1 visible

  // ---- enc_state @ inWih[:,128:256]^T once, cached as bf16 (hi) ----
  uint2 geh[4][4];
  {
    f32x4 acc[4][4];
#pragma unroll
    for (int g = 0; g < 4; ++g)
#pragma unroll
      for (int mt = 0; mt < 4; ++mt) acc[g][mt] = f32x4{0.f, 0.f, 0.f, 0.f};
    gemm_pk<4>(acc, bufB + 128, plX, pA, l, q);
#pragma unroll
    for (int g = 0; g < 4; ++g)
#pragma unroll
      for (int mt = 0; mt < 4; ++mt)
        geh[g][mt] = uint2{pk2(acc[g][mt][0], acc[g][mt][1]),
                           pk2(acc[g][mt][2], acc[g][mt][3])};
  }
  if (tid < 64) s_xc[tid] = (float)x[(size_t)(node0 + tid) * TT + (T_CTX - 1)];
  const float b2i = (float)w[O_B2];
  const float b2o = (float)w[O_B2 + 1];
  const float b1i = (float)w[O_HEADP + wid * 16 + l];
  const float w2i = (float)w[O_HEADP + 128 + wid * 16 + l];
  const float b1o = (float)w[O_HEADP + 256 + wid * 16 + l];
  const float w2o = (float)w[O_HEADP + 384 + wid * 16 + l];
  pA = preB(plD0);
  __syncthreads();                             // s_xc ready

  // ================= decoder =================
#pragma unroll 1
  for (int s = 0; s < HOR; ++s) {
    const int t = T_CTX + s;
    float v[10];
    v[0] = s_xc[nd];
    v[1] = cx; v[2] = cy;
#pragma unroll
    for (int e = 0; e < 7; ++e)
      v[3 + e] = (float)env[((size_t)(node0 + nd) * 7 + e) * TT + t];
    proj16(v, s_win + 1536, bufA, nd, sub);
    __syncthreads();                           // S1: bufA ready

    f32x4 acc[4][4];
#pragma unroll
    for (int g = 0; g < 4; ++g)
#pragma unroll
      for (int mt = 0; mt < 4; ++mt)
        acc[g][mt] = f32x4{uplo(geh[g][mt].x), uphi(geh[g][mt].x),
                           uplo(geh[g][mt].y), uphi(geh[g][mt].y)};
    gemm_pk<8>(acc, bufA, plD0, pA, l, q);
    PreB pC = preB(plD1);
    __syncthreads();                           // S2: bufA consumed
    cell_up<true>(acc, c0, bufB, bufA + 128, s_bias + 1024, wid, l, q);
    __syncthreads();                           // S3: bufB[0:128] ready

#pragma unroll
    for (int g = 0; g < 4; ++g)
#pragma unroll
      for (int mt = 0; mt < 4; ++mt) acc[g][mt] = f32x4{0.f, 0.f, 0.f, 0.f};
    gemm_pk<8>(acc, bufB, plD1, pC, l, q);
    bf16x8 hb[8];
#pragma unroll
    for (int f = 0; f < 8; ++f) hb[f] = *(const bf16x8*)(plH + f * 512);
    __syncthreads();                           // S4: bufB consumed
    cell_up<false>(acc, c1, bufB + 128, nullptr, s_bias + 1536, wid, l, q);
    if (tid < 128) s_red[tid] = 0.f;
    pA = preB(plD0);                           // next-step prefetch (static addrs)
    __syncthreads();                           // S5: h1 + s_red ready

    // ---- heads ----
    f32x4 hacc[2][4];
#pragma unroll
    for (int hd = 0; hd < 2; ++hd)
#pragma unroll
      for (int mt = 0; mt < 4; ++mt) hacc[hd][mt] = f32x4{0.f, 0.f, 0.f, 0.f};
#pragma unroll
    for (int kt = 0; kt < 4; ++kt) {
      bf16x8 a[4];
#pragma unroll
      for (int mt = 0; mt < 4; ++mt)
        a[mt] = *(const bf16x8*)(bufB + 128 + (mt * 16 + l) * SA + kt * 32 + q * 8);
#pragma unroll
      for (int mt = 0; mt < 4; ++mt) {
        hacc[0][mt] = MFMA(a[mt], hb[kt],     hacc[0][mt], 0, 0, 0);
        hacc[1][mt] = MFMA(a[mt], hb[4 + kt], hacc[1][mt], 0, 0, 0);
      }
    }
#pragma unroll
    for (int hd = 0; hd < 2; ++hd) {
      const float b1v = hd ? b1o : b1i;
      const float w2v = hd ? w2o : w2i;
#pragma unroll
      for (int mt = 0; mt < 4; ++mt)
#pragma unroll
        for (int r = 0; r < 4; ++r) {
          float val = fmaxf(hacc[hd][mt][r] + b1v, 0.f) * w2v;
          val += __shfl_xor(val, 1, 64);
          val += __shfl_xor(val, 2, 64);
          val += __shfl_xor(val, 4, 64);
          val += __shfl_xor(val, 8, 64);
          if (l == 0) atomicAdd(&s_red[hd * 64 + mt * 16 + q * 4 + r], val);
        }
    }
    __syncthreads();                           // S6: s_red complete
    if (tid < 64) {
      float xc = s_xc[tid];
      float si = sigm(s_red[tid] + b2i);
      float so = sigm(s_red[64 + tid] + b2o);
      float xn = xc + si - so * xc;
      s_xc[tid] = xn;
      out[(size_t)(node0 + tid) * HOR + s] = (T)xn;
    }
    __syncthreads();                           // S7: s_xc stable
  }
}

extern "C" void kernel_launch(void* const* d_in, const int* in_sizes, int n_in,
                              void* d_out, int out_size, void* d_ws, size_t ws_size,
                              hipStream_t stream) {
  (void)in_sizes; (void)n_in; (void)out_size; (void)ws_size;
  Ptrs P;
  for (int i = 0; i < 29; ++i) P.q[i] = d_in[i];
  int*    flag = (int*)d_ws;
  bf16_t* w    = (bf16_t*)d_ws;

  detect_kernel<<<1, 64, 0, stream>>>((const unsigned short*)d_in[4], flag);
  prep_kernel<<<256, 256, 0, stream>>>(P, w, flag);
  lstm_persist<float><<<256, NTH, 0, stream>>>(
      (const float*)d_in[0], (const float*)d_in[1], (const float*)d_in[2],
      w, flag, (float*)d_out);
  lstm_persist<bf16_t><<<256, NTH, 0, stream>>>(
      (const bf16_t*)d_in[0], (const bf16_t*)d_in[1], (const bf16_t*)d_in[2],
      w, flag, (bf16_t*)d_out);
}